// Round 2
// baseline (64.028 us; speedup 1.0000x reference)
//
#include <hip/hip_runtime.h>

// Problem constants (match the reference)
#define BATCH 64
#define FDIM  16
#define NDIM  128
#define FP    32
#define NEDGE (NDIM * (NDIM - 1))   // 16256
#define NEDGE4 (NEDGE / 4)          // 4064  (NEDGE % 4 == 0)
#define CHUNKS 8                    // blocks per batch
#define E4PB  (NEDGE4 / CHUNKS)     // 508 float4-outputs per block

// out[b,e] = s1[b, recv[e]] + s2[b, send[e]]
//   s1[b,n] = sum_f x[b,f,n] * v1[f],  v1[f] = sum_g a[g]      * w[g,f]
//   s2[b,n] = sum_f x[b,f,n] * v2[f],  v2[f] = sum_g a[FP + g] * w[g,f]
//
// Latency-oriented restructure:
//   - ALL global loads (x column, edge indices) issued at kernel entry, so
//     their latency overlaps the phase-1 v-fold instead of serializing
//     behind two barriers.
//   - phase 2 uses all 256 lanes (t<128 -> s1, t>=128 -> s2).
//   - grid.x=8 (was 16): half the redundant phase-1/2 recompute per batch;
//     2 float4 outputs per thread.
__global__ __launch_bounds__(256) void gat_edge_fused(
    const float* __restrict__ x,     // (B, F, N)
    const float* __restrict__ w,     // (FP, F)
    const float* __restrict__ a,     // (2*FP)
    const int*   __restrict__ recv,  // (NEDGE)
    const int*   __restrict__ send,  // (NEDGE)
    float*       __restrict__ out)   // (B, NEDGE)
{
    __shared__ float v1s[FDIM];
    __shared__ float v2s[FDIM];
    __shared__ float s1s[NDIM];
    __shared__ float s2s[NDIM];

    const int b = blockIdx.y;
    const int t = threadIdx.x;
    const int n = t & (NDIM - 1);

    // ---- Prefetch: issue every global load before any dependent compute ----
    // x column for this thread's node (consumed by phase 2, both halves)
    const float* xb = x + (size_t)b * (FDIM * NDIM) + n;
    float xv[FDIM];
#pragma unroll
    for (int f = 0; f < FDIM; ++f)
        xv[f] = xb[f * NDIM];

    // edge indices (consumed by phase 3); int4 = 4 edges per load
    const int e4_0 = blockIdx.x * E4PB + t;          // always < NEDGE4
    const int e4_1 = e4_0 + 256;
    const bool has1 = (t + 256) < E4PB;              // 508 -> lanes 252..255 idle on 2nd
    const int4 r0 = ((const int4*)recv)[e4_0];
    const int4 c0 = ((const int4*)send)[e4_0];
    int4 r1 = r0, c1 = c0;
    if (has1) {
        r1 = ((const int4*)recv)[e4_1];
        c1 = ((const int4*)send)[e4_1];
    }

    // ---- Phase 1: fold a into w -> v1, v2 (threads 0..31, 4-way ILP) ----
    if (t < 2 * FDIM) {
        const int f = t & (FDIM - 1);
        const float* av = a + ((t < FDIM) ? 0 : FP);
        float p0 = 0.f, p1 = 0.f, p2 = 0.f, p3 = 0.f;
#pragma unroll
        for (int g = 0; g < FP; g += 4) {
            p0 += av[g + 0] * w[(g + 0) * FDIM + f];
            p1 += av[g + 1] * w[(g + 1) * FDIM + f];
            p2 += av[g + 2] * w[(g + 2) * FDIM + f];
            p3 += av[g + 3] * w[(g + 3) * FDIM + f];
        }
        const float acc = (p0 + p1) + (p2 + p3);
        if (t < FDIM) v1s[f] = acc;
        else          v2s[f] = acc;
    }
    __syncthreads();

    // ---- Phase 2: per-node scores, all 256 threads ----
    // waves 0,1 (t<128) compute s1; waves 2,3 compute s2. vv is wave-uniform
    // so the LDS reads broadcast (conflict-free). x already in registers.
    {
        const float* vv = (t < NDIM) ? v1s : v2s;
        float p0 = 0.f, p1 = 0.f;
#pragma unroll
        for (int f = 0; f < FDIM; f += 2) {
            p0 += xv[f]     * vv[f];
            p1 += xv[f + 1] * vv[f + 1];
        }
        if (t < NDIM) s1s[n] = p0 + p1;
        else          s2s[n] = p0 + p1;
    }
    __syncthreads();

    // ---- Phase 3: gather-add, 2 float4 per thread, coalesced stores ----
    float4* ob = (float4*)(out + (size_t)b * NEDGE);
    float4 o;
    o.x = s1s[r0.x] + s2s[c0.x];
    o.y = s1s[r0.y] + s2s[c0.y];
    o.z = s1s[r0.z] + s2s[c0.z];
    o.w = s1s[r0.w] + s2s[c0.w];
    ob[e4_0] = o;
    if (has1) {
        o.x = s1s[r1.x] + s2s[c1.x];
        o.y = s1s[r1.y] + s2s[c1.y];
        o.z = s1s[r1.z] + s2s[c1.z];
        o.w = s1s[r1.w] + s2s[c1.w];
        ob[e4_1] = o;
    }
}

extern "C" void kernel_launch(void* const* d_in, const int* in_sizes, int n_in,
                              void* d_out, int out_size, void* d_ws, size_t ws_size,
                              hipStream_t stream) {
    const float* x    = (const float*)d_in[0];
    const float* w    = (const float*)d_in[1];
    const float* a    = (const float*)d_in[2];
    const int*   recv = (const int*)d_in[3];
    const int*   send = (const int*)d_in[4];
    float*       out  = (float*)d_out;

    dim3 grid(CHUNKS, BATCH);   // (8, 64) = 512 blocks, 2 resident per CU
    gat_edge_fused<<<grid, 256, 0, stream>>>(x, w, a, recv, send, out);
}